// Round 7
// baseline (456.758 us; speedup 1.0000x reference)
//
#include <hip/hip_runtime.h>

// Problem constants (from reference): z (64,128,64,64) f32, emb (256,128) f32
#define K_EMB   256
#define C_DIM   128
#define HW      4096            // 64*64
#define NPOS    262144          // 64*HW
#define Q_ELEMS 33554432        // 64*128*64*64
#define IDX_OFF Q_ELEMS         // idx chunk offset in d_out (floats)
#define LOSS_OFF (Q_ELEMS + NPOS)

#define BLKP 64                 // positions per block (z tile = 128c x 64p = 32 KB LDS)
#define NTHR 512                // 8 waves
#define TM   4                  // positions per thread
#define TN   8                  // codes per thread
#define NKG  32                 // k-groups (512 threads / 16 p-groups)

// ws layout (floats): [0,256) enorm, [256] loss accumulator, [512, 512+32768) embT (c*256+k)
#define WS_ENORM 0
#define WS_ACC   256
#define WS_EMBT  512
#define WS_NEED_FULL  ((WS_EMBT + C_DIM * K_EMB) * 4)

// ---------------------------------------------------------------------------
// Kernel A: parallel emb transpose (one block per c), zero loss accum.
// ---------------------------------------------------------------------------
__global__ __launch_bounds__(K_EMB) void vq_transpose(const float* __restrict__ emb,
                                                      float* __restrict__ ws,
                                                      int use_embT) {
    const int c = blockIdx.x, k = threadIdx.x;
    if (use_embT) ws[WS_EMBT + c * K_EMB + k] = emb[k * C_DIM + c];
    if (c == 0 && k == 0) ws[WS_ACC] = 0.f;
}

// ---------------------------------------------------------------------------
// Kernel B: per-code squared norms. Same ascending-c serial fmaf chain as the
// absmax-0 kernels (float4 components consumed in x,y,z,w = ascending c).
// ---------------------------------------------------------------------------
__global__ __launch_bounds__(K_EMB) void vq_enorm(const float* __restrict__ emb,
                                                  float* __restrict__ ws) {
    const int k = threadIdx.x;
    const float4* __restrict__ er = reinterpret_cast<const float4*>(emb + k * C_DIM);
    float s = 0.f;
    #pragma unroll
    for (int j = 0; j < C_DIM / 4; ++j) {
        float4 v = er[j];
        s = fmaf(v.x, v.x, s);
        s = fmaf(v.y, v.y, s);
        s = fmaf(v.z, v.z, s);
        s = fmaf(v.w, v.w, s);
    }
    ws[WS_ENORM + k] = s;
}

// ---------------------------------------------------------------------------
// Kernel 1: register-tile (4x8) GEMM + argmin, LDS z / global embT.
//
// R11 (this round): R5/R6 falsified the "more waves" family. Busy pinned at
// ~59% = 4 waves/SIMD x 66cyc/440cyc: the inner loop mixed SMEM (s_load
// embT) + DS (ds_read z), which share lgkmcnt; SMEM retires OUT-OF-ORDER so
// the only safe wait is lgkmcnt(0) -- a full ~370cyc drain every c-step, and
// no reachable wave count covers 5.6x. Fix: remove SMEM from the loop.
// Thread tile TM=4 pos x TN=8 codes: per c-step 1 ds_read_b128 (z, counted
// in-order lgkmcnt) + 2 global_load_dwordx4 (embT, counted in-order vmcnt)
// + 32 fmaf. Unroll 4 lets the compiler issue loads for c+1..c+3 under
// compute -- both counters support counted waits, so the drain disappears.
// Also: znorm 8x redundancy gone (computed once per position by wave 0,
// overlapped); thread FLOPs = 100% useful.
//
// Numerics: bit-identical to the absmax-0 lineage. acc[i][j] = one serial
// ascending-c fmaf chain per (pos,code); znorm = same serial ascending-c
// chain from bit-copied LDS z; enorm via LDS bit-copy; d = (znorm - 2*acc)
// + enorm[k]; strict < ascending k within thread (j asc), then strict <
// ascending k-group combine = global first-min. Loss epilogue byte-for-byte
// R6: wave-0 lanes own positions blk*64+0..63, same 128-term ascending-c
// chains, same shfl tree, same 4096 atomics.
// ---------------------------------------------------------------------------
template <int UT>
__global__ __launch_bounds__(NTHR, 4) void vq_main(const float* __restrict__ z,
                                                   const float* __restrict__ emb,
                                                   const float* __restrict__ ws,
                                                   float* __restrict__ out,
                                                   float* __restrict__ loss_acc) {
    __shared__ float zlds[C_DIM * BLKP];            // 32 KB [c][p]
    __shared__ float shz[BLKP];                     // znorm per position
    __shared__ float shen[K_EMB];                   // enorm bit-copy, 1 KB
    __shared__ float shpb[NKG * BLKP];              // partial bests, 8 KB
    __shared__ unsigned int shpi[NKG * BLKP / 4];   // packed u8 indices, 2 KB

    const int t   = threadIdx.x;
    const int pg  = t & 15;                    // position group
    const int p0  = pg * 4;
    const int kg  = t >> 4;                    // k-group 0..31
    const int k0  = kg * TN;
    const int blk = blockIdx.x;
    const int b   = blk >> 6;                  // 64 blocks per image
    const int hw0 = (blk & 63) * BLKP;
    const size_t zoff = (size_t)b * (C_DIM * HW) + hw0;
    const float* __restrict__ zsrc = z + zoff;

    const float* __restrict__ embT    = ws + WS_EMBT;
    const float* __restrict__ enorm_g = ws + WS_ENORM;

    // ---- Stage z tile into LDS (coalesced float4; [c][p]) + enorm copy ----
    {
        const float4* __restrict__ zs4 = reinterpret_cast<const float4*>(zsrc);
        float4* __restrict__ zl4 = reinterpret_cast<float4*>(zlds);
        #pragma unroll
        for (int j = 0; j < (C_DIM * BLKP / 4) / NTHR; ++j) {   // 4 iters
            const int i4 = t + j * NTHR;
            const int c  = i4 >> 4;            // 16 float4 per c-row (64 floats)
            const int p4 = i4 & 15;
            zl4[i4] = zs4[(size_t)c * (HW / 4) + p4];
        }
        if (t < K_EMB) shen[t] = enorm_g[t];   // bit-copy
    }
    __syncthreads();

    // ---- Wave 0: znorm pre-pass (one serial ascending-c chain per pos). ----
    // Runs while waves 1-7 proceed into the main loop; consumed only after
    // the post-loop barrier.
    if (t < BLKP) {
        float zn = 0.f;
        #pragma unroll 8
        for (int c = 0; c < C_DIM; ++c) {
            const float zc = zlds[c * BLKP + t];
            zn = fmaf(zc, zc, zn);             // same serial chain as lineage
        }
        shz[t] = zn;
    }

    // ---- Main register-tile loop: 1 ds_read_b128 + 2 dwordx4 + 32 fmaf ----
    float acc[TM][TN];
    #pragma unroll
    for (int i = 0; i < TM; ++i)
        #pragma unroll
        for (int j = 0; j < TN; ++j) acc[i][j] = 0.f;

    #pragma unroll 4
    for (int c = 0; c < C_DIM; ++c) {
        const float4 zv = *reinterpret_cast<const float4*>(&zlds[c * BLKP + p0]);
        float ev[TN];
        if (UT) {
            const float4* __restrict__ ep =
                reinterpret_cast<const float4*>(embT + c * K_EMB + k0);
            const float4 e0 = ep[0];
            const float4 e1 = ep[1];
            ev[0] = e0.x; ev[1] = e0.y; ev[2] = e0.z; ev[3] = e0.w;
            ev[4] = e1.x; ev[5] = e1.y; ev[6] = e1.z; ev[7] = e1.w;
        } else {
            #pragma unroll
            for (int j = 0; j < TN; ++j) ev[j] = emb[(k0 + j) * C_DIM + c];
        }
        const float zz[TM] = {zv.x, zv.y, zv.z, zv.w};
        #pragma unroll
        for (int i = 0; i < TM; ++i)
            #pragma unroll
            for (int j = 0; j < TN; ++j)
                acc[i][j] = fmaf(zz[i], ev[j], acc[i][j]);   // serial asc-c chains
    }
    __syncthreads();   // shz/zlds stable; all acc done

    // ---- Per-thread partial argmin (8 codes, ascending k, strict <) ----
    {
        float pb[TM];
        int   pi[TM];
        #pragma unroll
        for (int i = 0; i < TM; ++i) {
            const float zn = shz[p0 + i];
            float best = 3.402823466e38f;
            int   bi = 0;
            #pragma unroll
            for (int j = 0; j < TN; ++j) {
                const float d = (zn - 2.0f * acc[i][j]) + shen[k0 + j];
                if (d < best) { best = d; bi = k0 + j; }   // strict < = first-min
            }
            pb[i] = best; pi[i] = bi;
        }
        *reinterpret_cast<float4*>(&shpb[kg * BLKP + p0]) =
            make_float4(pb[0], pb[1], pb[2], pb[3]);
        shpi[kg * 16 + pg] = (unsigned)(pi[0] & 255) | ((unsigned)(pi[1] & 255) << 8)
                           | ((unsigned)(pi[2] & 255) << 16) | ((unsigned)(pi[3] & 255) << 24);
    }
    __syncthreads();

    if (t < BLKP) {   // wave 0: thread t owns position p = t
        const int p = t;
        // combine 32 k-groups in ascending order, strict < = global first-min
        float bb = shpb[p];
        int   bi = (shpi[p >> 2] >> ((p & 3) * 8)) & 255;
        #pragma unroll 4
        for (int g = 1; g < NKG; ++g) {
            const float bq = shpb[g * BLKP + p];
            const int   iq = (shpi[g * 16 + (p >> 2)] >> ((p & 3) * 8)) & 255;
            if (bq < bb) { bb = bq; bi = iq; }
        }
        const int fin = bi;
        const int pos = blk * BLKP + p;
        __builtin_nontemporal_store((float)fin, &out[IDX_OFF + pos]);

        // Epilogue: q = z + (e - z), loss += (e - z)^2. Byte-for-byte R6.
        float lsum = 0.f;
        float* qp = out + zoff + p;
        const float4* __restrict__ er =
            reinterpret_cast<const float4*>(emb + fin * C_DIM);
        #pragma unroll 4
        for (int j = 0; j < C_DIM / 4; ++j) {
            const float4 ev = er[j];
            const int c0 = j * 4;
            const float z0 = zlds[(c0 + 0) * BLKP + p];
            const float z1 = zlds[(c0 + 1) * BLKP + p];
            const float z2 = zlds[(c0 + 2) * BLKP + p];
            const float z3 = zlds[(c0 + 3) * BLKP + p];
            const float d0 = ev.x - z0, d1 = ev.y - z1;
            const float d2 = ev.z - z2, d3 = ev.w - z3;
            lsum = fmaf(d0, d0, lsum);
            lsum = fmaf(d1, d1, lsum);
            lsum = fmaf(d2, d2, lsum);
            lsum = fmaf(d3, d3, lsum);
            __builtin_nontemporal_store(z0 + d0, &qp[(size_t)(c0 + 0) * HW]);
            __builtin_nontemporal_store(z1 + d1, &qp[(size_t)(c0 + 1) * HW]);
            __builtin_nontemporal_store(z2 + d2, &qp[(size_t)(c0 + 2) * HW]);
            __builtin_nontemporal_store(z3 + d3, &qp[(size_t)(c0 + 3) * HW]);
        }

        // Wave-level reduction, one atomic per block (same 4096 partials).
        #pragma unroll
        for (int off = 32; off > 0; off >>= 1)
            lsum += __shfl_down(lsum, off, 64);
        if (p == 0) atomicAdd(loss_acc, lsum);
    }
}

// ---------------------------------------------------------------------------
// Kernel 2: finalize the two scalar losses.
// ---------------------------------------------------------------------------
__global__ void vq_finalize(const float* __restrict__ loss_acc,
                            float* __restrict__ out_losses) {
    float S = loss_acc[0];
    float mean = S / (float)Q_ELEMS;
    out_losses[0] = 0.25f * mean;  // commitment_loss
    out_losses[1] = mean;          // codebook_loss
}

extern "C" void kernel_launch(void* const* d_in, const int* in_sizes, int n_in,
                              void* d_out, int out_size, void* d_ws, size_t ws_size,
                              hipStream_t stream) {
    const float* z   = (const float*)d_in[0];
    const float* emb = (const float*)d_in[1];
    float* out = (float*)d_out;
    float* ws  = (float*)d_ws;

    int use_embT = (ws_size >= (size_t)WS_NEED_FULL) ? 1 : 0;

    vq_transpose<<<C_DIM, K_EMB, 0, stream>>>(emb, ws, use_embT);
    vq_enorm<<<1, K_EMB, 0, stream>>>(emb, ws);
    if (use_embT)
        vq_main<1><<<NPOS / BLKP, NTHR, 0, stream>>>(z, emb, ws, out, ws + WS_ACC);
    else
        vq_main<0><<<NPOS / BLKP, NTHR, 0, stream>>>(z, emb, ws, out, ws + WS_ACC);
    vq_finalize<<<1, 1, 0, stream>>>(ws + WS_ACC, out + LOSS_OFF);
}